// Round 9
// baseline (49914.142 us; speedup 1.0000x reference)
//
#include <hip/hip_runtime.h>
#include <hip/hip_fp16.h>

// MC-LSTM persistent recurrence, v9: 24 WGs x 512 threads (8 waves), 4 units
// each + o-gate as 97th unit on WG0. Tagged-data protocol (fp16|steptag u32,
// relaxed agent scope). Wave-autonomous rows: one syncthreads/step (norm only).
// Weights in padded LDS; x A-frags direct from global.

#define TT 2048
#define NWG 24

typedef _Float16 f16;
typedef _Float16 f16x8 __attribute__((ext_vector_type(8)));
typedef float f32x4 __attribute__((ext_vector_type(4)));

#define LD_RLX(p)   __hip_atomic_load((p), __ATOMIC_RELAXED, __HIP_MEMORY_SCOPE_AGENT)
#define ST_RLX(p,v) __hip_atomic_store((p), (v), __ATOMIC_RELAXED, __HIP_MEMORY_SCOPE_AGENT)

static __device__ __forceinline__ unsigned packf16(float v, unsigned tag) {
  f16 h = (f16)v;
  unsigned short s;
  __builtin_memcpy(&s, &h, 2);
  return ((unsigned)s << 16) | (tag & 0xffffu);
}
static __device__ __forceinline__ float unpackf16(unsigned u) {
  unsigned short s = (unsigned short)(u >> 16);
  f16 h;
  __builtin_memcpy(&h, &s, 2);
  return (float)h;
}
static __device__ __forceinline__ float f16bits(unsigned short s) {
  f16 h;
  __builtin_memcpy(&h, &s, 2);
  return (float)h;
}

// ---- ws layout (bytes) ----
#define OFF_WH   0u
#define SZ_WH    (97u * 8192u * 2u)                  // fp16 weights [unit][h][g]
#define OFF_PART ((OFF_WH + SZ_WH + 255u) & ~255u)   // 25 x [128][64] tagged u32
#define SZ_PART  (25u * 8192u * 4u)
#define OFF_CB   (OFF_PART + SZ_PART)                // [128][64] tagged u32 c
#define SZ_CB    (8192u * 4u)

__global__ void prep_kernel(const float* __restrict__ Wi, const float* __restrict__ Wr,
                            const float* __restrict__ Wo, f16* __restrict__ Wh) {
  int idx = blockIdx.x * 256 + threadIdx.x;
  if (idx >= 97 * 8192) return;
  int g = idx & 127, h = (idx >> 7) & 63, r = idx >> 13;
  float v;
  if (r < 32)      v = Wi[g * 2048 + r * 64 + h];
  else if (r < 96) v = Wr[g * 4096 + (r - 32) * 64 + h];
  else             v = Wo[g * 64 + h];
  Wh[idx] = (f16)v;
}

__launch_bounds__(512, 1)
__global__ void mclstm_kernel(const float* __restrict__ xm, const float* __restrict__ xa,
                              const float* __restrict__ bi, const float* __restrict__ br,
                              const float* __restrict__ bo, const f16* __restrict__ Wh,
                              unsigned* __restrict__ part, unsigned* __restrict__ cbuf,
                              float* __restrict__ out) {
  const int j = blockIdx.x, tid = threadIdx.x;
  const int w = tid >> 6, l = tid & 63, lr = l & 15, lk = l >> 4;
  const bool isO = (j == 0);   // carries o-gate as 5th unit
  const bool isI = (j < 8);    // units 4j..4j+3 all-i for j<8, else all-r

  __shared__ __align__(16) f16 WL[5][64][136];       // padded: 272B rows, 2-way max
  __shared__ __align__(16) f16 featC[128][72];       // cn cols (wave-private rows)
  __shared__ unsigned short cLr[128][72];            // raw c bits (wave-private rows)
  __shared__ float nred[8];

  for (int i = tid; i < 128 * 72; i += 512) {
    (&featC[0][0])[i] = (f16)0.f;
    (&cLr[0][0])[i] = 0;
  }
#pragma unroll
  for (int un = 0; un < 4; ++un) {
    const f16* src = Wh + (size_t)(4 * j + un) * 8192;
    for (int i = tid; i < 1024; i += 512)
      *(f16x8*)&WL[un][i >> 4][(i & 15) * 8] = *(const f16x8*)(src + i * 8);
  }
  if (isO) {
    const f16* src = Wh + (size_t)96 * 8192;
    for (int i = tid; i < 1024; i += 512)
      *(f16x8*)&WL[4][i >> 4][(i & 15) * 8] = *(const f16x8*)(src + i * 8);
  }

  float bu[4][4], bo4[4];
#pragma unroll
  for (int un = 0; un < 4; ++un) {
    int u = 4 * j + un;
#pragma unroll
    for (int ht = 0; ht < 4; ++ht) {
      int col = ht * 16 + lr;
      bu[un][ht] = (u < 32) ? bi[u * 64 + col] : br[(u - 32) * 64 + col];
    }
  }
#pragma unroll
  for (int ht = 0; ht < 4; ++ht) bo4[ht] = isO ? bo[ht * 16 + lr] : 0.f;
  __syncthreads();

  const int arow = 16 * w + lr;  // this lane's A-fragment row (wave-own b-tile)

  f32x4 xm4[2], xa4[2];
  {
    const float* bx = xm + (size_t)arow * 32 + lk * 8;
    xm4[0] = *(const f32x4*)bx; xm4[1] = *(const f32x4*)(bx + 4);
    const float* ba = xa + (size_t)arow * 32 + lk * 8;
    xa4[0] = *(const f32x4*)ba; xa4[1] = *(const f32x4*)(ba + 4);
  }

  f32x4 acc[4][4], aco[4];
  {  // x-GEMM for t=0 (direct-from-global A frags)
    f16x8 A0, A1;
#pragma unroll
    for (int i = 0; i < 4; ++i) {
      A0[i] = (f16)xm4[0][i]; A0[4 + i] = (f16)xm4[1][i];
      A1[i] = (f16)xa4[0][i]; A1[4 + i] = (f16)xa4[1][i];
    }
#pragma unroll
    for (int un = 0; un < 4; ++un)
#pragma unroll
      for (int ht = 0; ht < 4; ++ht) {
        f16x8 B0 = *(const f16x8*)&WL[un][ht * 16 + lr][lk * 8];
        f16x8 B1 = *(const f16x8*)&WL[un][ht * 16 + lr][32 + lk * 8];
        f32x4 a = (f32x4){0.f, 0.f, 0.f, 0.f};
        a = __builtin_amdgcn_mfma_f32_16x16x32_f16(A0, B0, a, 0, 0, 0);
        a = __builtin_amdgcn_mfma_f32_16x16x32_f16(A1, B1, a, 0, 0, 0);
        acc[un][ht] = a;
      }
#pragma unroll
    for (int ht = 0; ht < 4; ++ht) {
      f32x4 a = (f32x4){0.f, 0.f, 0.f, 0.f};
      if (isO) {
        f16x8 B0 = *(const f16x8*)&WL[4][ht * 16 + lr][lk * 8];
        f16x8 B1 = *(const f16x8*)&WL[4][ht * 16 + lr][32 + lk * 8];
        a = __builtin_amdgcn_mfma_f32_16x16x32_f16(A0, B0, a, 0, 0, 0);
        a = __builtin_amdgcn_mfma_f32_16x16x32_f16(A1, B1, a, 0, 0, 0);
      }
      aco[ht] = a;
    }
  }

  for (int t = 0; t < TT; ++t) {
    // ---- (a) issue x[t+1] loads (latency hides under the c-poll) ----
    if (t + 1 < TT) {
      const float* bx = xm + (size_t)(t + 1) * 4096 + arow * 32 + lk * 8;
      xm4[0] = *(const f32x4*)bx; xm4[1] = *(const f32x4*)(bx + 4);
      const float* ba = xa + (size_t)(t + 1) * 4096 + arow * 32 + lk * 8;
      xa4[0] = *(const f32x4*)ba; xa4[1] = *(const f32x4*)(ba + 4);
    }

    // ---- (b) wave polls its OWN 16 rows of tagged c; global norm; stage ----
    if (t > 0) {
      const unsigned want = (unsigned)t & 0xffffu;
      unsigned cv[16];
      for (;;) {
#pragma unroll
        for (int k = 0; k < 16; ++k) cv[k] = LD_RLX(cbuf + 1024 * w + 64 * k + l);
        unsigned m = 0;
#pragma unroll
        for (int k = 0; k < 16; ++k) m |= (cv[k] ^ want) & 0xffffu;
        if (m == 0) break;
        __builtin_amdgcn_s_sleep(1);
      }
      float ns = 0.f;
#pragma unroll
      for (int k = 0; k < 16; ++k) ns += fabsf(unpackf16(cv[k]));
      ns += __shfl_xor(ns, 1, 64);
      ns += __shfl_xor(ns, 2, 64);
      ns += __shfl_xor(ns, 4, 64);
      ns += __shfl_xor(ns, 8, 64);
      ns += __shfl_xor(ns, 16, 64);
      ns += __shfl_xor(ns, 32, 64);
      if (l == 0) nred[w] = ns;
      __syncthreads();  // the ONE barrier per step (global norm)
      float nm = 0.f;
#pragma unroll
      for (int p = 0; p < 8; ++p) nm += nred[p];
      const float inv = __builtin_amdgcn_rcpf(nm + 1e-5f);
#pragma unroll
      for (int k = 0; k < 16; ++k) {
        float cr = unpackf16(cv[k]);
        featC[16 * w + k][l] = (f16)(cr * inv);
        cLr[16 * w + k][l] = (unsigned short)(cv[k] >> 16);
      }
    }

    // ---- (c) cn-part GEMM (reads only wave-own featC rows) ----
    {
      f16x8 A2 = *(const f16x8*)&featC[arow][lk * 8];
      f16x8 A3 = *(const f16x8*)&featC[arow][32 + lk * 8];
#pragma unroll
      for (int un = 0; un < 4; ++un)
#pragma unroll
        for (int ht = 0; ht < 4; ++ht) {
          f16x8 B2 = *(const f16x8*)&WL[un][ht * 16 + lr][64 + lk * 8];
          f16x8 B3 = *(const f16x8*)&WL[un][ht * 16 + lr][96 + lk * 8];
          acc[un][ht] = __builtin_amdgcn_mfma_f32_16x16x32_f16(A2, B2, acc[un][ht], 0, 0, 0);
          acc[un][ht] = __builtin_amdgcn_mfma_f32_16x16x32_f16(A3, B3, acc[un][ht], 0, 0, 0);
        }
      if (isO) {
#pragma unroll
        for (int ht = 0; ht < 4; ++ht) {
          f16x8 B2 = *(const f16x8*)&WL[4][ht * 16 + lr][64 + lk * 8];
          f16x8 B3 = *(const f16x8*)&WL[4][ht * 16 + lr][96 + lk * 8];
          aco[ht] = __builtin_amdgcn_mfma_f32_16x16x32_f16(A2, B2, aco[ht], 0, 0, 0);
          aco[ht] = __builtin_amdgcn_mfma_f32_16x16x32_f16(A3, B3, aco[ht], 0, 0, 0);
        }
      }
    }

    // ---- (d) epilogue: sigmoid, L1-norm over h, scale, sum units, store ----
    {
      const float* xmtp = xm + (size_t)t * 4096;
      const unsigned tagp = (unsigned)(t + 1);
      float contrib[4][4];
#pragma unroll
      for (int ht = 0; ht < 4; ++ht)
#pragma unroll
        for (int rr = 0; rr < 4; ++rr) contrib[ht][rr] = 0.f;
#pragma unroll
      for (int un = 0; un < 4; ++un) {
        const int u = 4 * j + un;
#pragma unroll
        for (int rr = 0; rr < 4; ++rr) {
          const int b = 16 * w + lk * 4 + rr;
          float s4[4], sum = 0.f;
#pragma unroll
          for (int ht = 0; ht < 4; ++ht) {
            float z = acc[un][ht][rr] + bu[un][ht];
            float sg = __builtin_amdgcn_rcpf(1.0f + __expf(-z));
            s4[ht] = sg;
            sum += sg;
          }
          float r4 = sum;
          r4 += __shfl_xor(r4, 1, 64);
          r4 += __shfl_xor(r4, 2, 64);
          r4 += __shfl_xor(r4, 4, 64);
          r4 += __shfl_xor(r4, 8, 64);
          float wr = isI ? xmtp[b * 32 + u] : f16bits(cLr[b][u - 32]);
          float sc = wr * __builtin_amdgcn_rcpf(fmaxf(r4, 1e-12f));
#pragma unroll
          for (int ht = 0; ht < 4; ++ht) contrib[ht][rr] += s4[ht] * sc;
        }
      }
#pragma unroll
      for (int ht = 0; ht < 4; ++ht)
#pragma unroll
        for (int rr = 0; rr < 4; ++rr) {
          const int b = 16 * w + lk * 4 + rr;
          ST_RLX(&part[(size_t)j * 8192 + b * 64 + ht * 16 + lr],
                 packf16(contrib[ht][rr], tagp));
        }
      if (isO) {
#pragma unroll
        for (int ht = 0; ht < 4; ++ht)
#pragma unroll
          for (int rr = 0; rr < 4; ++rr) {
            float z = aco[ht][rr] + bo4[ht];
            float sg = __builtin_amdgcn_rcpf(1.0f + __expf(-z));
            const int b = 16 * w + lk * 4 + rr;
            ST_RLX(&part[(size_t)24 * 8192 + b * 64 + ht * 16 + lr], packf16(sg, tagp));
          }
      }
    }

    // ---- (e) x-GEMM for t+1 (overlaps other WGs' part stores) ----
    if (t + 1 < TT) {
      f16x8 A0, A1;
#pragma unroll
      for (int i = 0; i < 4; ++i) {
        A0[i] = (f16)xm4[0][i]; A0[4 + i] = (f16)xm4[1][i];
        A1[i] = (f16)xa4[0][i]; A1[4 + i] = (f16)xa4[1][i];
      }
#pragma unroll
      for (int un = 0; un < 4; ++un)
#pragma unroll
        for (int ht = 0; ht < 4; ++ht) {
          f16x8 B0 = *(const f16x8*)&WL[un][ht * 16 + lr][lk * 8];
          f16x8 B1 = *(const f16x8*)&WL[un][ht * 16 + lr][32 + lk * 8];
          f32x4 a = (f32x4){0.f, 0.f, 0.f, 0.f};
          a = __builtin_amdgcn_mfma_f32_16x16x32_f16(A0, B0, a, 0, 0, 0);
          a = __builtin_amdgcn_mfma_f32_16x16x32_f16(A1, B1, a, 0, 0, 0);
          acc[un][ht] = a;
        }
      if (isO) {
#pragma unroll
        for (int ht = 0; ht < 4; ++ht) {
          f16x8 B0 = *(const f16x8*)&WL[4][ht * 16 + lr][lk * 8];
          f16x8 B1 = *(const f16x8*)&WL[4][ht * 16 + lr][32 + lk * 8];
          f32x4 a = (f32x4){0.f, 0.f, 0.f, 0.f};
          a = __builtin_amdgcn_mfma_f32_16x16x32_f16(A0, B0, a, 0, 0, 0);
          a = __builtin_amdgcn_mfma_f32_16x16x32_f16(A1, B1, a, 0, 0, 0);
          aco[ht] = a;
        }
      }
    }

    // ---- (f) reduce own slice: poll 25 tagged words/element; publish c ----
    {
      const int e = 342 * j + tid;
      if (tid < 342 && e < 8192) {
        const unsigned want = (unsigned)(t + 1) & 0xffffu;
        unsigned pv[25];
        for (;;) {
#pragma unroll
          for (int p = 0; p < 25; ++p) pv[p] = LD_RLX(part + (size_t)p * 8192 + e);
          unsigned m = 0;
#pragma unroll
          for (int p = 0; p < 25; ++p) m |= (pv[p] ^ want) & 0xffffu;
          if (m == 0) break;
          __builtin_amdgcn_s_sleep(1);
        }
        float mn = 0.f;
#pragma unroll
        for (int p = 0; p < 24; ++p) mn += unpackf16(pv[p]);
        float ov = unpackf16(pv[24]);
        float cn_ = (1.0f - ov) * mn;
        ST_RLX(&cbuf[e], packf16(cn_, (unsigned)(t + 1)));
        ST_RLX(&out[(size_t)t * 8192 + e], ov * mn);
        ST_RLX(&out[(size_t)(TT + t) * 8192 + e], cn_);
      }
    }
  }
}

extern "C" void kernel_launch(void* const* d_in, const int* in_sizes, int n_in,
                              void* d_out, int out_size, void* d_ws, size_t ws_size,
                              hipStream_t stream) {
  (void)in_sizes; (void)n_in; (void)out_size; (void)ws_size;
  const float* xm = (const float*)d_in[0];
  const float* xa = (const float*)d_in[1];
  const float* Wi = (const float*)d_in[2];
  const float* bi = (const float*)d_in[3];
  const float* Wr = (const float*)d_in[4];
  const float* br = (const float*)d_in[5];
  const float* Wo = (const float*)d_in[6];
  const float* bo = (const float*)d_in[7];

  char* ws = (char*)d_ws;
  f16* Wh        = (f16*)(ws + OFF_WH);
  unsigned* part = (unsigned*)(ws + OFF_PART);
  unsigned* cbuf = (unsigned*)(ws + OFF_CB);

  // Clear parts per launch (stale-tag hygiene across graph replays); cbuf is
  // collision-free by tag arithmetic (and deterministic values regardless).
  hipMemsetAsync(ws + OFF_PART, 0, SZ_PART, stream);
  prep_kernel<<<(97 * 8192 + 255) / 256, 256, 0, stream>>>(Wi, Wr, Wo, Wh);
  mclstm_kernel<<<NWG, 512, 0, stream>>>(xm, xa, bi, br, bo, Wh, part, cbuf,
                                         (float*)d_out);
}

// Round 10
// 23537.703 us; speedup vs baseline: 2.1206x; 2.1206x over previous
//
#include <hip/hip_runtime.h>
#include <hip/hip_fp16.h>

// MC-LSTM persistent recurrence, v10: 2-D shard = 8 b-slices x 7 unit-shards
// (56 WGs x 512 thr). All cross-WG coupling except the scalar L1 norm is
// b-local: per-step exchanges are a [1024][7] tagged slab per b-slice
// (fan-in 7), a 4KB tagged c tile per b-slice, and 8 tagged norm words.
// Tagged-data protocol (f16 value | 16-bit step tag), relaxed agent scope.

#define TT 2048
#define NBS 8
#define NUS 7
#define NWG 56

typedef _Float16 f16;
typedef _Float16 f16x8 __attribute__((ext_vector_type(8)));
typedef float f32x4 __attribute__((ext_vector_type(4)));

#define LD_RLX(p)   __hip_atomic_load((p), __ATOMIC_RELAXED, __HIP_MEMORY_SCOPE_AGENT)
#define ST_RLX(p,v) __hip_atomic_store((p), (v), __ATOMIC_RELAXED, __HIP_MEMORY_SCOPE_AGENT)

static __device__ __forceinline__ unsigned packf16(float v, unsigned tag) {
  f16 h = (f16)v;
  unsigned short s;
  __builtin_memcpy(&s, &h, 2);
  return ((unsigned)s << 16) | (tag & 0xffffu);
}
static __device__ __forceinline__ float f16bits(unsigned short s) {
  f16 h;
  __builtin_memcpy(&h, &s, 2);
  return (float)h;
}
static __device__ __forceinline__ unsigned short f16of(float v) {
  f16 h = (f16)v;
  unsigned short s;
  __builtin_memcpy(&s, &h, 2);
  return s;
}

// ---- ws layout (bytes) ----
#define OFF_WH   0u
#define SZ_WH    (97u * 8192u * 2u)                   // fp16 weights [unit][h][g]
#define OFF_SLAB ((OFF_WH + SZ_WH + 255u) & ~255u)    // [8 bs][1024 e][8 col] u32
#define SZ_SLAB  (NBS * 1024u * 8u * 4u)
#define OFF_CB   (OFF_SLAB + SZ_SLAB)                 // [8 bs][1024 e] tagged u32
#define SZ_CB    (NBS * 1024u * 4u)
#define OFF_NS   (OFF_CB + SZ_CB)                     // [2 slot][8 bs] tagged u32
#define SZ_NS    (2u * NBS * 4u)
#define ZERO_OFF OFF_SLAB
#define ZERO_LEN (SZ_SLAB + SZ_CB + SZ_NS)

__global__ void prep_kernel(const float* __restrict__ Wi, const float* __restrict__ Wr,
                            const float* __restrict__ Wo, f16* __restrict__ Wh) {
  int idx = blockIdx.x * 256 + threadIdx.x;
  if (idx >= 97 * 8192) return;
  int g = idx & 127, h = (idx >> 7) & 63, r = idx >> 13;
  float v;
  if (r < 32)      v = Wi[g * 2048 + r * 64 + h];
  else if (r < 96) v = Wr[g * 4096 + (r - 32) * 64 + h];
  else             v = Wo[g * 64 + h];
  Wh[idx] = (f16)v;
}

__launch_bounds__(512, 1)
__global__ void mclstm_kernel(const float* __restrict__ xm, const float* __restrict__ xa,
                              const float* __restrict__ bi, const float* __restrict__ br,
                              const float* __restrict__ bo, const f16* __restrict__ Wh,
                              unsigned* __restrict__ slab, unsigned* __restrict__ cbuf,
                              unsigned* __restrict__ nslab, float* __restrict__ out) {
  const int j = blockIdx.x, tid = threadIdx.x;
  const int us = j % NUS, bs = j / NUS;
  const int w = tid >> 6, l = tid & 63, lr = l & 15, lk = l >> 4;
  const bool isO = (us == 6), isRed = (us == 0);

  __shared__ unsigned short craw[16][88];  // raw c bits (this b-slice), padded rows
  __shared__ float pslab[8][1024];         // per-wave partial [16b][64h]
  __shared__ float nred[8];

  for (int i = tid; i < 16 * 88; i += 512) (&craw[0][0])[i] = 0;

  // ---- persistent weights in registers: 2 units per wave (us6 clamps to o) ----
  f16x8 Bf[2][4][4];
  float bu[2][4];
#pragma unroll
  for (int un = 0; un < 2; ++un) {
    int u = us * 16 + 2 * w + un;
    if (u > 96) u = 96;
    if (isO) u = 96;
#pragma unroll
    for (int ht = 0; ht < 4; ++ht) {
      int col = ht * 16 + lr;
      bu[un][ht] = (u < 32) ? bi[u * 64 + col]
                 : (u < 96) ? br[(u - 32) * 64 + col] : bo[col];
#pragma unroll
      for (int kk = 0; kk < 4; ++kk)
        Bf[un][ht][kk] = *(const f16x8*)(Wh + (size_t)u * 8192 + col * 128 + kk * 32 + lk * 8);
    }
  }

  // x prefetch (this lane's A-frag source: row bs*16+lr, cols lk*8..+8)
  const size_t xoff = (size_t)(bs * 16 + lr) * 32 + lk * 8;
  f32x4 xA0 = *(const f32x4*)(xm + xoff), xA1 = *(const f32x4*)(xm + xoff + 4);
  f32x4 xB0 = *(const f32x4*)(xa + xoff), xB1 = *(const f32x4*)(xa + xoff + 4);
  __syncthreads();

  float inv = 0.f;  // t=0: c==0
  for (int t = 0; t < TT; ++t) {
    // ---- (b) consume c[t] + norm ----
    if (t > 0) {
      const unsigned want = (unsigned)t & 0xffffu;
      const unsigned* nsb = nslab + (t & 1) * NBS;
      unsigned nv[8], cv0 = 0, cv1 = 0;
      if (isRed) {
        for (;;) {
#pragma unroll
          for (int k = 0; k < 8; ++k) nv[k] = LD_RLX(nsb + k);
          unsigned m = 0;
#pragma unroll
          for (int k = 0; k < 8; ++k) m |= (nv[k] ^ want) & 0xffffu;
          if (m == 0) break;
          __builtin_amdgcn_s_sleep(1);
        }
      } else {
        const unsigned* cb = cbuf + bs * 1024 + 2 * tid;
        for (;;) {
          cv0 = LD_RLX(cb);
          cv1 = LD_RLX(cb + 1);
#pragma unroll
          for (int k = 0; k < 8; ++k) nv[k] = LD_RLX(nsb + k);
          unsigned m = ((cv0 ^ want) | (cv1 ^ want)) & 0xffffu;
#pragma unroll
          for (int k = 0; k < 8; ++k) m |= (nv[k] ^ want) & 0xffffu;
          if (m == 0) break;
          __builtin_amdgcn_s_sleep(1);
        }
        const int e = 2 * tid, b = e >> 6, h = e & 63;
        craw[b][h] = (unsigned short)(cv0 >> 16);
        craw[b][h + 1] = (unsigned short)(cv1 >> 16);
      }
      float nm = 0.f;
#pragma unroll
      for (int k = 0; k < 8; ++k) nm += f16bits((unsigned short)(nv[k] >> 16));
      inv = __builtin_amdgcn_rcpf(nm + 1e-5f);
    }
    __syncthreads();  // craw staged (or reducer-staged last step) before A-build

    // ---- (d) A-frags + GEMM ----
    f16x8 A0, A1, A2, A3;
#pragma unroll
    for (int i = 0; i < 4; ++i) {
      A0[i] = (f16)xA0[i]; A0[4 + i] = (f16)xA1[i];
      A1[i] = (f16)xB0[i]; A1[4 + i] = (f16)xB1[i];
    }
    {
      const unsigned short* cr = &craw[lr][0];
#pragma unroll
      for (int i = 0; i < 8; ++i) A2[i] = (f16)(f16bits(cr[lk * 8 + i]) * inv);
#pragma unroll
      for (int i = 0; i < 8; ++i) A3[i] = (f16)(f16bits(cr[32 + lk * 8 + i]) * inv);
    }
    if (t + 1 < TT) {  // issue x[t+1] prefetch now; consumed next iteration
      const float* bx = xm + (size_t)(t + 1) * 4096 + xoff;
      const float* ba = xa + (size_t)(t + 1) * 4096 + xoff;
      xA0 = *(const f32x4*)bx; xA1 = *(const f32x4*)(bx + 4);
      xB0 = *(const f32x4*)ba; xB1 = *(const f32x4*)(ba + 4);
    }
    f32x4 acc[2][4];
#pragma unroll
    for (int un = 0; un < 2; ++un)
#pragma unroll
      for (int ht = 0; ht < 4; ++ht) {
        f32x4 a = (f32x4){0.f, 0.f, 0.f, 0.f};
        a = __builtin_amdgcn_mfma_f32_16x16x32_f16(A0, Bf[un][ht][0], a, 0, 0, 0);
        a = __builtin_amdgcn_mfma_f32_16x16x32_f16(A1, Bf[un][ht][1], a, 0, 0, 0);
        a = __builtin_amdgcn_mfma_f32_16x16x32_f16(A2, Bf[un][ht][2], a, 0, 0, 0);
        a = __builtin_amdgcn_mfma_f32_16x16x32_f16(A3, Bf[un][ht][3], a, 0, 0, 0);
        acc[un][ht] = a;
      }

    // ---- (e) epilogue -> per-wave partial in pslab ----
    if (!isO) {
      const float* xmtp = xm + (size_t)t * 4096;
      float contrib[4][4];
#pragma unroll
      for (int ht = 0; ht < 4; ++ht)
#pragma unroll
        for (int rr = 0; rr < 4; ++rr) contrib[ht][rr] = 0.f;
#pragma unroll
      for (int un = 0; un < 2; ++un) {
        const int u = us * 16 + 2 * w + un;
        const bool isI = (u < 32);
        const int kidx = u - 32;
#pragma unroll
        for (int rr = 0; rr < 4; ++rr) {
          const int b = lk * 4 + rr;
          float s4[4], sum = 0.f;
#pragma unroll
          for (int ht = 0; ht < 4; ++ht) {
            float z = acc[un][ht][rr] + bu[un][ht];
            float sg = __builtin_amdgcn_rcpf(1.0f + __expf(-z));
            s4[ht] = sg;
            sum += sg;
          }
          float r4 = sum;
          r4 += __shfl_xor(r4, 1, 64);
          r4 += __shfl_xor(r4, 2, 64);
          r4 += __shfl_xor(r4, 4, 64);
          r4 += __shfl_xor(r4, 8, 64);
          float wr = isI ? xmtp[(size_t)(bs * 16 + b) * 32 + u] : f16bits(craw[b][kidx]);
          float sc = wr * __builtin_amdgcn_rcpf(fmaxf(r4, 1e-12f));
#pragma unroll
          for (int ht = 0; ht < 4; ++ht) contrib[ht][rr] += s4[ht] * sc;
        }
      }
#pragma unroll
      for (int ht = 0; ht < 4; ++ht)
#pragma unroll
        for (int rr = 0; rr < 4; ++rr)
          pslab[w][(lk * 4 + rr) * 64 + ht * 16 + lr] = contrib[ht][rr];
    } else if (w == 0) {  // o-unit: sigmoid only
#pragma unroll
      for (int ht = 0; ht < 4; ++ht)
#pragma unroll
        for (int rr = 0; rr < 4; ++rr) {
          float z = acc[0][ht][rr] + bu[0][ht];
          pslab[0][(lk * 4 + rr) * 64 + ht * 16 + lr] =
              __builtin_amdgcn_rcpf(1.0f + __expf(-z));
        }
    }
    __syncthreads();

    // ---- (f) intra-WG sum + tagged slab-column store (2 elements/thread) ----
    {
      const int e0 = 2 * tid;
      float v0 = 0.f, v1 = 0.f;
      if (!isO) {
#pragma unroll
        for (int p = 0; p < 8; ++p) {
          float2 pv = *(const float2*)&pslab[p][e0];
          v0 += pv.x;
          v1 += pv.y;
        }
      } else {
        float2 pv = *(const float2*)&pslab[0][e0];
        v0 = pv.x;
        v1 = pv.y;
      }
      const unsigned tg = (unsigned)(t + 1);
      ST_RLX(slab + (size_t)bs * 8192 + e0 * 8 + us, packf16(v0, tg));
      ST_RLX(slab + (size_t)bs * 8192 + (e0 + 1) * 8 + us, packf16(v1, tg));
    }

    // ---- (g) reducer: poll 7 cols x 2 elems; combine; publish c + norm ----
    if (isRed) {
      const int e0 = 2 * tid;
      const unsigned want = (unsigned)(t + 1) & 0xffffu;
      const unsigned* base = slab + (size_t)bs * 8192;
      unsigned pv[14];
      for (;;) {
#pragma unroll
        for (int c = 0; c < 7; ++c) {
          pv[c] = LD_RLX(base + e0 * 8 + c);
          pv[7 + c] = LD_RLX(base + (e0 + 1) * 8 + c);
        }
        unsigned m = 0;
#pragma unroll
        for (int c = 0; c < 14; ++c) m |= (pv[c] ^ want) & 0xffffu;
        if (m == 0) break;
        __builtin_amdgcn_s_sleep(1);
      }
      float mn0 = 0.f, mn1 = 0.f;
#pragma unroll
      for (int c = 0; c < 6; ++c) {
        mn0 += f16bits((unsigned short)(pv[c] >> 16));
        mn1 += f16bits((unsigned short)(pv[7 + c] >> 16));
      }
      const float ov0 = f16bits((unsigned short)(pv[6] >> 16));
      const float ov1 = f16bits((unsigned short)(pv[13] >> 16));
      const float cn0 = (1.0f - ov0) * mn0, cn1 = (1.0f - ov1) * mn1;
      const int b = e0 >> 6, h = e0 & 63;
      const int bg = bs * 16 + b;
      out[(size_t)t * 8192 + bg * 64 + h] = ov0 * mn0;
      out[(size_t)t * 8192 + bg * 64 + h + 1] = ov1 * mn1;
      out[(size_t)(TT + t) * 8192 + bg * 64 + h] = cn0;
      out[(size_t)(TT + t) * 8192 + bg * 64 + h + 1] = cn1;
      const unsigned short h0 = f16of(cn0), h1 = f16of(cn1);
      craw[b][h] = h0;  // direct self-stage (skip cbuf round-trip)
      craw[b][h + 1] = h1;
      ST_RLX(cbuf + bs * 1024 + e0, ((unsigned)h0 << 16) | ((t + 1) & 0xffffu));
      ST_RLX(cbuf + bs * 1024 + e0 + 1, ((unsigned)h1 << 16) | ((t + 1) & 0xffffu));
      // norm partial from the f16-rounded c (what consumers use)
      float ns = fabsf(f16bits(h0)) + fabsf(f16bits(h1));
      ns += __shfl_xor(ns, 1, 64);
      ns += __shfl_xor(ns, 2, 64);
      ns += __shfl_xor(ns, 4, 64);
      ns += __shfl_xor(ns, 8, 64);
      ns += __shfl_xor(ns, 16, 64);
      ns += __shfl_xor(ns, 32, 64);
      if (l == 0) nred[w] = ns;
      __syncthreads();
      if (tid == 0) {
        float nsum = 0.f;
#pragma unroll
        for (int p = 0; p < 8; ++p) nsum += nred[p];
        ST_RLX(nslab + ((t + 1) & 1) * NBS + bs, packf16(nsum, (unsigned)(t + 1)));
      }
    }
  }
}

extern "C" void kernel_launch(void* const* d_in, const int* in_sizes, int n_in,
                              void* d_out, int out_size, void* d_ws, size_t ws_size,
                              hipStream_t stream) {
  (void)in_sizes; (void)n_in; (void)out_size; (void)ws_size;
  const float* xm = (const float*)d_in[0];
  const float* xa = (const float*)d_in[1];
  const float* Wi = (const float*)d_in[2];
  const float* bi = (const float*)d_in[3];
  const float* Wr = (const float*)d_in[4];
  const float* br = (const float*)d_in[5];
  const float* Wo = (const float*)d_in[6];
  const float* bo = (const float*)d_in[7];

  char* ws = (char*)d_ws;
  f16* Wh         = (f16*)(ws + OFF_WH);
  unsigned* slab  = (unsigned*)(ws + OFF_SLAB);
  unsigned* cbuf  = (unsigned*)(ws + OFF_CB);
  unsigned* nslab = (unsigned*)(ws + OFF_NS);

  // Tag hygiene across graph replays: clear slab+cbuf+nslab (tags would
  // otherwise collide with this run's wants).
  hipMemsetAsync(ws + ZERO_OFF, 0, ZERO_LEN, stream);
  prep_kernel<<<(97 * 8192 + 255) / 256, 256, 0, stream>>>(Wi, Wr, Wo, Wh);
  mclstm_kernel<<<NWG, 512, 0, stream>>>(xm, xa, bi, br, bo, Wh, slab, cbuf, nslab,
                                         (float*)d_out);
}

// Round 11
// 17651.642 us; speedup vs baseline: 2.8277x; 1.3335x over previous
//
#include <hip/hip_runtime.h>
#include <hip/hip_fp16.h>

// MC-LSTM persistent recurrence, v11: 8 b-slices x 7 unit-shards (56 WGs x 512).
// ONE cross-WG hop per step: double-buffered tagged slab ([slot][bs][us][1024],
// col-major coalesced); every WG redundantly reduces its OWN b-slice (c never
// crosses WGs). Scalar L1 norm published as 8 tagged words and consumed LATE:
// GEMM runs on raw c, inv applied in the epilogue (z = accX + inv*accC + b).

#define TT 2048
#define NBS 8
#define NUS 7
#define NWG 56

typedef _Float16 f16;
typedef _Float16 f16x8 __attribute__((ext_vector_type(8)));
typedef float f32x4 __attribute__((ext_vector_type(4)));

#define LD_RLX(p)   __hip_atomic_load((p), __ATOMIC_RELAXED, __HIP_MEMORY_SCOPE_AGENT)
#define ST_RLX(p,v) __hip_atomic_store((p), (v), __ATOMIC_RELAXED, __HIP_MEMORY_SCOPE_AGENT)

static __device__ __forceinline__ unsigned packf16(float v, unsigned tag) {
  f16 h = (f16)v;
  unsigned short s;
  __builtin_memcpy(&s, &h, 2);
  return ((unsigned)s << 16) | (tag & 0xffffu);
}
static __device__ __forceinline__ float unpackf16(unsigned u) {
  unsigned short s = (unsigned short)(u >> 16);
  f16 h;
  __builtin_memcpy(&h, &s, 2);
  return (float)h;
}
static __device__ __forceinline__ float f16bits(unsigned short s) {
  f16 h;
  __builtin_memcpy(&h, &s, 2);
  return (float)h;
}
static __device__ __forceinline__ unsigned short f16of(float v) {
  f16 h = (f16)v;
  unsigned short s;
  __builtin_memcpy(&s, &h, 2);
  return s;
}

// ---- ws layout (bytes) ----
#define OFF_WH   0u
#define SZ_WH    (97u * 8192u * 2u)                    // fp16 weights [unit][h][g]
#define OFF_SLAB ((OFF_WH + SZ_WH + 255u) & ~255u)     // [2 slot][8 bs][7 us][1024] u32
#define SZ_SLAB  (2u * NBS * NUS * 1024u * 4u)
#define OFF_NS   (OFF_SLAB + SZ_SLAB)                  // [2 slot][8 bs] tagged u32
#define SZ_NS    (2u * NBS * 4u)
#define ZERO_OFF OFF_SLAB
#define ZERO_LEN (SZ_SLAB + SZ_NS)

__global__ void prep_kernel(const float* __restrict__ Wi, const float* __restrict__ Wr,
                            const float* __restrict__ Wo, f16* __restrict__ Wh) {
  int idx = blockIdx.x * 256 + threadIdx.x;
  if (idx >= 97 * 8192) return;
  int g = idx & 127, h = (idx >> 7) & 63, r = idx >> 13;
  float v;
  if (r < 32)      v = Wi[g * 2048 + r * 64 + h];
  else if (r < 96) v = Wr[g * 4096 + (r - 32) * 64 + h];
  else             v = Wo[g * 64 + h];
  Wh[idx] = (f16)v;
}

__launch_bounds__(512, 1)
__global__ void mclstm_kernel(const float* __restrict__ xm, const float* __restrict__ xa,
                              const float* __restrict__ bi, const float* __restrict__ br,
                              const float* __restrict__ bo, const f16* __restrict__ Wh,
                              unsigned* __restrict__ slab, unsigned* __restrict__ nslab,
                              float* __restrict__ out) {
  const int j = blockIdx.x, tid = threadIdx.x;
  const int us = j % NUS, bs = j / NUS;
  const int w = tid >> 6, l = tid & 63, lr = l & 15, lk = l >> 4;
  const bool isO = (us == 6);

  __shared__ unsigned short craw[16][88];  // raw c bits (this b-slice), padded rows
  __shared__ float pslab[8][1024];         // per-wave contrib partials
  __shared__ float nredL[8];
  __shared__ float invS;

  for (int i = tid; i < 16 * 88; i += 512) (&craw[0][0])[i] = 0;
  if (tid == 0) invS = 0.f;

  // ---- persistent weights in registers: 2 units per wave (us6 -> o unit 96) ----
  f16x8 Bf[2][4][4];
  float bu[2][4];
#pragma unroll
  for (int un = 0; un < 2; ++un) {
    int u = isO ? 96 : us * 16 + 2 * w + un;
#pragma unroll
    for (int ht = 0; ht < 4; ++ht) {
      int col = ht * 16 + lr;
      bu[un][ht] = (u < 32) ? bi[u * 64 + col]
                 : (u < 96) ? br[(u - 32) * 64 + col] : bo[col];
#pragma unroll
      for (int kk = 0; kk < 4; ++kk)
        Bf[un][ht][kk] = *(const f16x8*)(Wh + (size_t)u * 8192 + col * 128 + kk * 32 + lk * 8);
    }
  }

  const size_t xoff = (size_t)(bs * 16 + lr) * 32 + lk * 8;
  f32x4 xA0 = *(const f32x4*)(xm + xoff), xA1 = *(const f32x4*)(xm + xoff + 4);
  f32x4 xB0 = *(const f32x4*)(xa + xoff), xB1 = *(const f32x4*)(xa + xoff + 4);
  __syncthreads();

  for (int t = 0; t <= TT; ++t) {
    // ---- phase 1: poll own b-slice slab (tag t); local reduce; stage craw ----
    if (t > 0) {
      const unsigned want = (unsigned)t & 0xffffu;
      const unsigned* base = slab + ((size_t)(t & 1) * NBS + bs) * (NUS * 1024);
      const int e0 = 2 * tid;
      unsigned pv[14];
      for (;;) {
#pragma unroll
        for (int c = 0; c < 7; ++c) {
          pv[c] = LD_RLX(base + c * 1024 + e0);
          pv[7 + c] = LD_RLX(base + c * 1024 + e0 + 1);
        }
        unsigned m = 0;
#pragma unroll
        for (int c = 0; c < 14; ++c) m |= (pv[c] ^ want) & 0xffffu;
        if (m == 0) break;
        __builtin_amdgcn_s_sleep(1);
      }
      float mn0 = 0.f, mn1 = 0.f;
#pragma unroll
      for (int c = 0; c < 6; ++c) {
        mn0 += unpackf16(pv[c]);
        mn1 += unpackf16(pv[7 + c]);
      }
      const float ov0 = unpackf16(pv[6]), ov1 = unpackf16(pv[13]);
      const float cn0 = (1.0f - ov0) * mn0, cn1 = (1.0f - ov1) * mn1;
      const unsigned short h0 = f16of(cn0), h1 = f16of(cn1);
      const int b = e0 >> 6, h = e0 & 63;
      craw[b][h] = h0;
      craw[b][h + 1] = h1;
      if (isO) {
        // norm partial (from the f16-rounded c all WGs will use) -> publish fast
        float ns = fabsf(f16bits(h0)) + fabsf(f16bits(h1));
        ns += __shfl_xor(ns, 1, 64);
        ns += __shfl_xor(ns, 2, 64);
        ns += __shfl_xor(ns, 4, 64);
        ns += __shfl_xor(ns, 8, 64);
        ns += __shfl_xor(ns, 16, 64);
        ns += __shfl_xor(ns, 32, 64);
        if (l == 0) nredL[w] = ns;
        __syncthreads();
        if (tid == 0) {
          float nsum = 0.f;
#pragma unroll
          for (int p = 0; p < 8; ++p) nsum += nredL[p];
          ST_RLX(nslab + (t & 1) * NBS + bs, packf16(nsum, (unsigned)t));
        }
        // out writes for step t-1 (off critical path)
        const int bg = bs * 16 + b;
        out[(size_t)(t - 1) * 8192 + bg * 64 + h] = ov0 * mn0;
        out[(size_t)(t - 1) * 8192 + bg * 64 + h + 1] = ov1 * mn1;
        out[(size_t)(TT + t - 1) * 8192 + bg * 64 + h] = cn0;
        out[(size_t)(TT + t - 1) * 8192 + bg * 64 + h + 1] = cn1;
      }
    }
    if (t == TT) break;
    __syncthreads();  // B1: craw staged

    // ---- phase 3: A-frags (raw c, NO inv) + dual-accumulator GEMM ----
    f16x8 A0, A1, A2, A3;
#pragma unroll
    for (int i = 0; i < 4; ++i) {
      A0[i] = (f16)xA0[i]; A0[4 + i] = (f16)xA1[i];
      A1[i] = (f16)xB0[i]; A1[4 + i] = (f16)xB1[i];
    }
    {
      const unsigned short* cr = &craw[lr][0];
#pragma unroll
      for (int i = 0; i < 8; ++i) A2[i] = *(const f16*)&cr[lk * 8 + i];
#pragma unroll
      for (int i = 0; i < 8; ++i) A3[i] = *(const f16*)&cr[32 + lk * 8 + i];
    }
    if (t + 1 < TT) {
      const float* bx = xm + (size_t)(t + 1) * 4096 + xoff;
      const float* ba = xa + (size_t)(t + 1) * 4096 + xoff;
      xA0 = *(const f32x4*)bx; xA1 = *(const f32x4*)(bx + 4);
      xB0 = *(const f32x4*)ba; xB1 = *(const f32x4*)(ba + 4);
    }
    f32x4 aX[2][4], aC[2][4];
    if (!isO || w == 0) {
#pragma unroll
      for (int un = 0; un < 2; ++un)
#pragma unroll
        for (int ht = 0; ht < 4; ++ht) {
          f32x4 a = (f32x4){0.f, 0.f, 0.f, 0.f};
          a = __builtin_amdgcn_mfma_f32_16x16x32_f16(A0, Bf[un][ht][0], a, 0, 0, 0);
          a = __builtin_amdgcn_mfma_f32_16x16x32_f16(A1, Bf[un][ht][1], a, 0, 0, 0);
          aX[un][ht] = a;
          f32x4 c = (f32x4){0.f, 0.f, 0.f, 0.f};
          c = __builtin_amdgcn_mfma_f32_16x16x32_f16(A2, Bf[un][ht][2], c, 0, 0, 0);
          c = __builtin_amdgcn_mfma_f32_16x16x32_f16(A3, Bf[un][ht][3], c, 0, 0, 0);
          aC[un][ht] = c;
        }
    }

    // ---- phase 4: wave0 polls the 8 norm words (overlapped with GEMM above) ----
    if (t > 0 && w == 0) {
      const unsigned want = (unsigned)t & 0xffffu;
      const unsigned* nsb = nslab + (t & 1) * NBS;
      unsigned v;
      for (;;) {
        v = (l < NBS) ? LD_RLX(nsb + l) : want;
        if (__all((int)((v & 0xffffu) == want))) break;
        __builtin_amdgcn_s_sleep(1);
      }
      float ns = (l < NBS) ? unpackf16(v) : 0.f;
      ns += __shfl_xor(ns, 1, 64);
      ns += __shfl_xor(ns, 2, 64);
      ns += __shfl_xor(ns, 4, 64);
      if (l == 0) invS = __builtin_amdgcn_rcpf(ns + 1e-5f);
    }
    __syncthreads();  // B2: invS visible
    const float inv = invS;

    // ---- phase 5: epilogue z = aX + inv*aC + b ----
    if (!isO) {
      const float* xmtp = xm + (size_t)t * 4096;
      float contrib[4][4];
#pragma unroll
      for (int ht = 0; ht < 4; ++ht)
#pragma unroll
        for (int rr = 0; rr < 4; ++rr) contrib[ht][rr] = 0.f;
#pragma unroll
      for (int un = 0; un < 2; ++un) {
        const int u = us * 16 + 2 * w + un;
        const bool isI = (u < 32);
        const int kidx = u - 32;
#pragma unroll
        for (int rr = 0; rr < 4; ++rr) {
          const int b = lk * 4 + rr;
          float s4[4], sum = 0.f;
#pragma unroll
          for (int ht = 0; ht < 4; ++ht) {
            float z = aX[un][ht][rr] + inv * aC[un][ht][rr] + bu[un][ht];
            float sg = __builtin_amdgcn_rcpf(1.0f + __expf(-z));
            s4[ht] = sg;
            sum += sg;
          }
          float r4 = sum;
          r4 += __shfl_xor(r4, 1, 64);
          r4 += __shfl_xor(r4, 2, 64);
          r4 += __shfl_xor(r4, 4, 64);
          r4 += __shfl_xor(r4, 8, 64);
          float wr = isI ? xmtp[(size_t)(bs * 16 + b) * 32 + u] : f16bits(craw[b][kidx]);
          float sc = wr * __builtin_amdgcn_rcpf(fmaxf(r4, 1e-12f));
#pragma unroll
          for (int ht = 0; ht < 4; ++ht) contrib[ht][rr] += s4[ht] * sc;
        }
      }
#pragma unroll
      for (int ht = 0; ht < 4; ++ht)
#pragma unroll
        for (int rr = 0; rr < 4; ++rr)
          pslab[w][(lk * 4 + rr) * 64 + ht * 16 + lr] = contrib[ht][rr];
    } else if (w == 0) {
#pragma unroll
      for (int ht = 0; ht < 4; ++ht)
#pragma unroll
        for (int rr = 0; rr < 4; ++rr) {
          float z = aX[0][ht][rr] + inv * aC[0][ht][rr] + bu[0][ht];
          pslab[0][(lk * 4 + rr) * 64 + ht * 16 + lr] =
              __builtin_amdgcn_rcpf(1.0f + __expf(-z));
        }
    }
    __syncthreads();  // B3: pslab complete

    // ---- phase 6: intra-WG sum -> coalesced tagged column store ----
    {
      const int e0 = 2 * tid;
      float v0, v1;
      if (!isO) {
        v0 = 0.f; v1 = 0.f;
#pragma unroll
        for (int p = 0; p < 8; ++p) {
          float2 pv2 = *(const float2*)&pslab[p][e0];
          v0 += pv2.x;
          v1 += pv2.y;
        }
      } else {
        float2 pv2 = *(const float2*)&pslab[0][e0];
        v0 = pv2.x;
        v1 = pv2.y;
      }
      const unsigned tg = (unsigned)(t + 1);
      unsigned* dst = slab + ((size_t)((t + 1) & 1) * NBS + bs) * (NUS * 1024) + us * 1024;
      ST_RLX(dst + e0, packf16(v0, tg));
      ST_RLX(dst + e0 + 1, packf16(v1, tg));
    }
    __syncthreads();  // B4: WAR (craw reads in phase 5 vs next phase-1 writes)
  }
}

extern "C" void kernel_launch(void* const* d_in, const int* in_sizes, int n_in,
                              void* d_out, int out_size, void* d_ws, size_t ws_size,
                              hipStream_t stream) {
  (void)in_sizes; (void)n_in; (void)out_size; (void)ws_size;
  const float* xm = (const float*)d_in[0];
  const float* xa = (const float*)d_in[1];
  const float* Wi = (const float*)d_in[2];
  const float* bi = (const float*)d_in[3];
  const float* Wr = (const float*)d_in[4];
  const float* br = (const float*)d_in[5];
  const float* Wo = (const float*)d_in[6];
  const float* bo = (const float*)d_in[7];

  char* ws = (char*)d_ws;
  f16* Wh         = (f16*)(ws + OFF_WH);
  unsigned* slab  = (unsigned*)(ws + OFF_SLAB);
  unsigned* nslab = (unsigned*)(ws + OFF_NS);

  // Tag hygiene across graph replays (stale tags would alias this run's wants).
  hipMemsetAsync(ws + ZERO_OFF, 0, ZERO_LEN, stream);
  prep_kernel<<<(97 * 8192 + 255) / 256, 256, 0, stream>>>(Wi, Wr, Wo, Wh);
  mclstm_kernel<<<NWG, 512, 0, stream>>>(xm, xa, bi, br, bo, Wh, slab, nslab,
                                         (float*)d_out);
}